// Round 2
// baseline (448.054 us; speedup 1.0000x reference)
//
#include <hip/hip_runtime.h>

typedef __bf16 bf16x8 __attribute__((ext_vector_type(8)));
typedef float  f32x4  __attribute__((ext_vector_type(4)));
typedef unsigned int u32x4 __attribute__((ext_vector_type(4)));

#define B_   2
#define N_   512
#define ND_  256
#define ED_  64
#define NH_  8
#define DH_  32

static __device__ __forceinline__ bf16x8 pack8(float4 a, float4 b) {
    bf16x8 r;
    r[0] = (__bf16)a.x; r[1] = (__bf16)a.y; r[2] = (__bf16)a.z; r[3] = (__bf16)a.w;
    r[4] = (__bf16)b.x; r[5] = (__bf16)b.y; r[6] = (__bf16)b.z; r[7] = (__bf16)b.w;
    return r;
}

// ---------------- prep kernel 1: edge-weight fp32 -> bf16 ----------------
// W16 layout: [3][256][64] (m, n=out, k=in) — exactly W's own [out][in] layout.
__global__ __launch_bounds__(256) void cvt_w_kernel(
    const float* __restrict__ wq, const float* __restrict__ wk,
    const float* __restrict__ wv, unsigned short* __restrict__ w16)
{
    int id = blockIdx.x * 256 + threadIdx.x;          // 0..49151
    const float* src = (id < 16384) ? wq : (id < 32768 ? wk : wv);
    int idx = id & 16383;
    w16[id] = __builtin_bit_cast(unsigned short, (__bf16)src[idx]);
}

// ---------------- prep kernel 2: node projections with folded biases -----
__global__ __launch_bounds__(256) void qkv_kernel(
    const float* __restrict__ node,
    const float* __restrict__ Wq, const float* __restrict__ bq,
    const float* __restrict__ Wk, const float* __restrict__ bk,
    const float* __restrict__ Wv, const float* __restrict__ bv,
    const float* __restrict__ beq, const float* __restrict__ bek,
    const float* __restrict__ bev,
    float* __restrict__ Q, float* __restrict__ K, float* __restrict__ V)
{
    __shared__ float xs[4][ND_];
    const int c  = threadIdx.x;                // output column 0..255
    const int g0 = blockIdx.x * 4;             // 4 rows of [B*N] per block
    #pragma unroll
    for (int rr = 0; rr < 4; rr++) xs[rr][c] = node[(size_t)(g0 + rr) * ND_ + c];
    __syncthreads();

    float aq[4] = {}, ak[4] = {}, av[4] = {};
    const float4* wqr = reinterpret_cast<const float4*>(Wq + (size_t)c * ND_);
    const float4* wkr = reinterpret_cast<const float4*>(Wk + (size_t)c * ND_);
    const float4* wvr = reinterpret_cast<const float4*>(Wv + (size_t)c * ND_);
    for (int k4 = 0; k4 < ND_ / 4; k4++) {
        float4 wqv = wqr[k4], wkv = wkr[k4], wvv = wvr[k4];
        #pragma unroll
        for (int rr = 0; rr < 4; rr++) {
            const float4 x = *reinterpret_cast<const float4*>(&xs[rr][k4 * 4]);
            aq[rr] += x.x*wqv.x + x.y*wqv.y + x.z*wqv.z + x.w*wqv.w;
            ak[rr] += x.x*wkv.x + x.y*wkv.y + x.z*wkv.z + x.w*wkv.w;
            av[rr] += x.x*wvv.x + x.y*wvv.y + x.z*wvv.z + x.w*wvv.w;
        }
    }
    float bqv = bq[c] + beq[c];
    float bkv = bk[c] + bek[c];
    float bvv = bv[c] + bev[c];
    #pragma unroll
    for (int rr = 0; rr < 4; rr++) {
        size_t o = (size_t)(g0 + rr) * ND_ + c;
        Q[o] = aq[rr] + bqv;
        K[o] = ak[rr] + bkv;
        V[o] = av[rr] + bvv;
    }
}

// ---------------- main fused kernel: one block per (b,i) -----------------
// 8 waves / block, wave w = head w. NO LDS, NO barriers: each wave loads its
// e-fragments straight from global (L1 serves the 8-way cross-wave reuse).
// MFMA computes D = W(A-operand) x e(B-operand), so C/D layout has
// j across the 16 lanes (col=l15) and d across quads/regs (row=q4*4+r).
__global__ __launch_bounds__(512) void attn_kernel(
    const float* __restrict__ edge,
    const float* __restrict__ Q, const float* __restrict__ K,
    const float* __restrict__ V, const unsigned short* __restrict__ W16,
    float* __restrict__ out)
{
    const int tid  = threadIdx.x;
    const int lane = tid & 63;
    const int w    = tid >> 6;       // wave id == head
    const int q4   = lane >> 4;      // quad
    const int l15  = lane & 15;
    const int blk  = blockIdx.x;
    const int b    = blk >> 9;
    const int i    = blk & (N_ - 1);

    // W fragments as MFMA A-operand: A[m=l15][k=q4*8+jj]
    // wf[m][half][ks]: lane holds W16[m][w*32 + half*16 + l15][ks*32 + q4*8 .. +7]
    bf16x8 wf[3][2][2];
    #pragma unroll
    for (int m = 0; m < 3; m++)
        #pragma unroll
        for (int h = 0; h < 2; h++)
            #pragma unroll
            for (int ks = 0; ks < 2; ks++) {
                const u32x4* p = reinterpret_cast<const u32x4*>(
                    W16 + m * (ND_ * ED_) + (w * DH_ + h * 16 + l15) * ED_ + ks * 32 + q4 * 8);
                wf[m][h][ks] = __builtin_bit_cast(bf16x8, *p);
            }

    // Q values for this lane's d-rows: d = h*16 + q4*4 + r
    const float* Qrow = Q + (size_t)(b * N_ + i) * ND_ + w * DH_;
    const float4 Qa = *reinterpret_cast<const float4*>(Qrow + q4 * 4);
    const float4 Qb = *reinterpret_cast<const float4*>(Qrow + 16 + q4 * 4);

    const float* Kbase = K + (size_t)b * N_ * ND_ + w * DH_ + q4 * 4;
    const float* Vbase = V + (size_t)b * N_ * ND_ + w * DH_ + q4 * 4;
    const float* ebase = edge + (size_t)blk * N_ * ED_;

    float m_run = -INFINITY, l_run = 0.f;
    float oA0 = 0.f, oA1 = 0.f, oA2 = 0.f, oA3 = 0.f;
    float oB0 = 0.f, oB1 = 0.f, oB2 = 0.f, oB3 = 0.f;
    const float scale = 0.17677669529663687f;   // 1/sqrt(32)
    const f32x4 z = {0.f, 0.f, 0.f, 0.f};

    #pragma unroll 1
    for (int jt = 0; jt < N_ / 16; jt++) {
        const int jb = jt * 16;
        const int j  = jb + l15;

        // e B-fragments: B[k=q4*8+jj][n=l15] = e[j][k], 8 consecutive k per lane
        const float* erow = ebase + (size_t)j * ED_ + q4 * 8;
        const float4 e0 = *reinterpret_cast<const float4*>(erow);
        const float4 e1 = *reinterpret_cast<const float4*>(erow + 4);
        const float4 e2 = *reinterpret_cast<const float4*>(erow + 32);
        const float4 e3 = *reinterpret_cast<const float4*>(erow + 36);

        // K/V rows for this lane's j, this lane's d-chunk (vectorized)
        const float* Krow = Kbase + (size_t)j * ND_;
        const float* Vrow = Vbase + (size_t)j * ND_;
        const float4 Ka  = *reinterpret_cast<const float4*>(Krow);
        const float4 Kb4 = *reinterpret_cast<const float4*>(Krow + 16);
        const float4 Va  = *reinterpret_cast<const float4*>(Vrow);
        const float4 Vb4 = *reinterpret_cast<const float4*>(Vrow + 16);

        const bf16x8 a0 = pack8(e0, e1);   // ks=0 (k 0..31)
        const bf16x8 a1 = pack8(e2, e3);   // ks=1 (k 32..63)

        f32x4 eqA = __builtin_amdgcn_mfma_f32_16x16x32_bf16(wf[0][0][0], a0, z, 0, 0, 0);
        f32x4 eqB = __builtin_amdgcn_mfma_f32_16x16x32_bf16(wf[0][1][0], a0, z, 0, 0, 0);
        f32x4 ekA = __builtin_amdgcn_mfma_f32_16x16x32_bf16(wf[1][0][0], a0, z, 0, 0, 0);
        f32x4 ekB = __builtin_amdgcn_mfma_f32_16x16x32_bf16(wf[1][1][0], a0, z, 0, 0, 0);
        eqA = __builtin_amdgcn_mfma_f32_16x16x32_bf16(wf[0][0][1], a1, eqA, 0, 0, 0);
        eqB = __builtin_amdgcn_mfma_f32_16x16x32_bf16(wf[0][1][1], a1, eqB, 0, 0, 0);
        ekA = __builtin_amdgcn_mfma_f32_16x16x32_bf16(wf[1][0][1], a1, ekA, 0, 0, 0);
        ekB = __builtin_amdgcn_mfma_f32_16x16x32_bf16(wf[1][1][1], a1, ekB, 0, 0, 0);

        // score for this lane's j: sum over d (4 regs x 2 halves here, quads via shfl)
        float t = (eqA[0] + Qa.x) * (ekA[0] + Ka.x)
                + (eqA[1] + Qa.y) * (ekA[1] + Ka.y)
                + (eqA[2] + Qa.z) * (ekA[2] + Ka.z)
                + (eqA[3] + Qa.w) * (ekA[3] + Ka.w)
                + (eqB[0] + Qb.x) * (ekB[0] + Kb4.x)
                + (eqB[1] + Qb.y) * (ekB[1] + Kb4.y)
                + (eqB[2] + Qb.z) * (ekB[2] + Kb4.z)
                + (eqB[3] + Qb.w) * (ekB[3] + Kb4.w);
        t += __shfl_xor(t, 16, 64);
        t += __shfl_xor(t, 32, 64);
        const float s = t * scale;

        float tmax = s;
        tmax = fmaxf(tmax, __shfl_xor(tmax, 1, 64));
        tmax = fmaxf(tmax, __shfl_xor(tmax, 2, 64));
        tmax = fmaxf(tmax, __shfl_xor(tmax, 4, 64));
        tmax = fmaxf(tmax, __shfl_xor(tmax, 8, 64));
        const float m_new = fmaxf(m_run, tmax);
        const float alpha = __expf(m_run - m_new);
        const float p = __expf(s - m_new);
        float psum = p;
        psum += __shfl_xor(psum, 1, 64);
        psum += __shfl_xor(psum, 2, 64);
        psum += __shfl_xor(psum, 4, 64);
        psum += __shfl_xor(psum, 8, 64);
        l_run = l_run * alpha + psum;
        m_run = m_new;

        f32x4 evA = __builtin_amdgcn_mfma_f32_16x16x32_bf16(wf[2][0][0], a0, z, 0, 0, 0);
        f32x4 evB = __builtin_amdgcn_mfma_f32_16x16x32_bf16(wf[2][1][0], a0, z, 0, 0, 0);
        evA = __builtin_amdgcn_mfma_f32_16x16x32_bf16(wf[2][0][1], a1, evA, 0, 0, 0);
        evB = __builtin_amdgcn_mfma_f32_16x16x32_bf16(wf[2][1][1], a1, evB, 0, 0, 0);

        oA0 = oA0 * alpha + p * (evA[0] + Va.x);
        oA1 = oA1 * alpha + p * (evA[1] + Va.y);
        oA2 = oA2 * alpha + p * (evA[2] + Va.z);
        oA3 = oA3 * alpha + p * (evA[3] + Va.w);
        oB0 = oB0 * alpha + p * (evB[0] + Vb4.x);
        oB1 = oB1 * alpha + p * (evB[1] + Vb4.y);
        oB2 = oB2 * alpha + p * (evB[2] + Vb4.z);
        oB3 = oB3 * alpha + p * (evB[3] + Vb4.w);
    }

    // reduce the PV partials over j (= l15 lanes); xor 1,2,4,8 stays in-quad
    #pragma unroll
    for (int mask = 1; mask <= 8; mask <<= 1) {
        oA0 += __shfl_xor(oA0, mask, 64);
        oA1 += __shfl_xor(oA1, mask, 64);
        oA2 += __shfl_xor(oA2, mask, 64);
        oA3 += __shfl_xor(oA3, mask, 64);
        oB0 += __shfl_xor(oB0, mask, 64);
        oB1 += __shfl_xor(oB1, mask, 64);
        oB2 += __shfl_xor(oB2, mask, 64);
        oB3 += __shfl_xor(oB3, mask, 64);
    }
    const float inv = 1.f / l_run;
    if (l15 == 0) {
        float* orow = out + (size_t)(b * N_ + i) * ND_ + w * DH_ + q4 * 4;
        float4 va = {oA0 * inv, oA1 * inv, oA2 * inv, oA3 * inv};
        float4 vb = {oB0 * inv, oB1 * inv, oB2 * inv, oB3 * inv};
        *reinterpret_cast<float4*>(orow)      = va;
        *reinterpret_cast<float4*>(orow + 16) = vb;
    }
}

extern "C" void kernel_launch(void* const* d_in, const int* in_sizes, int n_in,
                              void* d_out, int out_size, void* d_ws, size_t ws_size,
                              hipStream_t stream) {
    const float* node = (const float*)d_in[0];
    const float* edge = (const float*)d_in[1];
    const float* Wnq  = (const float*)d_in[2];
    const float* bnq  = (const float*)d_in[3];
    const float* Wnk  = (const float*)d_in[4];
    const float* bnk  = (const float*)d_in[5];
    const float* Wnv  = (const float*)d_in[6];
    const float* bnv  = (const float*)d_in[7];
    const float* Weq  = (const float*)d_in[8];
    const float* beq  = (const float*)d_in[9];
    const float* Wek  = (const float*)d_in[10];
    const float* bek  = (const float*)d_in[11];
    const float* Wev  = (const float*)d_in[12];
    const float* bev  = (const float*)d_in[13];

    char* ws = (char*)d_ws;
    unsigned short* W16 = (unsigned short*)ws;              // 3*256*64*2 = 96 KB
    float* Q = (float*)(ws + 131072);                       // 1 MB each
    float* K = Q + (size_t)B_ * N_ * ND_;
    float* V = K + (size_t)B_ * N_ * ND_;
    float* out = (float*)d_out;

    cvt_w_kernel<<<192, 256, 0, stream>>>(Weq, Wek, Wev, W16);
    qkv_kernel<<<(B_ * N_) / 4, 256, 0, stream>>>(node, Wnq, bnq, Wnk, bnk, Wnv, bnv,
                                                  beq, bek, bev, Q, K, V);
    attn_kernel<<<B_ * N_, 512, 0, stream>>>(edge, Q, K, V, W16, out);
}

// Round 3
// 409.563 us; speedup vs baseline: 1.0940x; 1.0940x over previous
//
#include <hip/hip_runtime.h>

typedef __bf16 bf16x8 __attribute__((ext_vector_type(8)));
typedef float  f32x4  __attribute__((ext_vector_type(4)));
typedef unsigned int u32x4 __attribute__((ext_vector_type(4)));

#define B_   2
#define N_   512
#define ND_  256
#define ED_  64
#define NH_  8
#define DH_  32

static __device__ __forceinline__ unsigned pack_bf16(float a, float b) {
    unsigned short ua = __builtin_bit_cast(unsigned short, (__bf16)a);
    unsigned short ub = __builtin_bit_cast(unsigned short, (__bf16)b);
    return (unsigned)ua | ((unsigned)ub << 16);
}

// ---------------- prep kernel 1: edge-weight fp32 -> bf16 ----------------
// W16 layout: [3][256][64] (m, n=out, k=in) — exactly W's own [out][in] layout.
__global__ __launch_bounds__(256) void cvt_w_kernel(
    const float* __restrict__ wq, const float* __restrict__ wk,
    const float* __restrict__ wv, unsigned short* __restrict__ w16)
{
    int id = blockIdx.x * 256 + threadIdx.x;          // 0..49151
    const float* src = (id < 16384) ? wq : (id < 32768 ? wk : wv);
    int idx = id & 16383;
    w16[id] = __builtin_bit_cast(unsigned short, (__bf16)src[idx]);
}

// ------- prep kernel 2: node projections, folded biases, HEAD-SPLIT ------
// Qh/Kh/Vh layout: [b*NH+h][N][DH] fp32 (matches MFMA C-operand load shape)
__global__ __launch_bounds__(256) void qkv_kernel(
    const float* __restrict__ node,
    const float* __restrict__ Wq, const float* __restrict__ bq,
    const float* __restrict__ Wk, const float* __restrict__ bk,
    const float* __restrict__ Wv, const float* __restrict__ bv,
    const float* __restrict__ beq, const float* __restrict__ bek,
    const float* __restrict__ bev,
    float* __restrict__ Qh, float* __restrict__ Kh, float* __restrict__ Vh)
{
    __shared__ float xs[4][ND_];
    const int c  = threadIdx.x;                // output column 0..255
    const int g0 = blockIdx.x * 4;             // 4 rows of [B*N] per block
    #pragma unroll
    for (int rr = 0; rr < 4; rr++) xs[rr][c] = node[(size_t)(g0 + rr) * ND_ + c];
    __syncthreads();

    float aq[4] = {}, ak[4] = {}, av[4] = {};
    const float4* wqr = reinterpret_cast<const float4*>(Wq + (size_t)c * ND_);
    const float4* wkr = reinterpret_cast<const float4*>(Wk + (size_t)c * ND_);
    const float4* wvr = reinterpret_cast<const float4*>(Wv + (size_t)c * ND_);
    for (int k4 = 0; k4 < ND_ / 4; k4++) {
        float4 wqv = wqr[k4], wkv = wkr[k4], wvv = wvr[k4];
        #pragma unroll
        for (int rr = 0; rr < 4; rr++) {
            const float4 x = *reinterpret_cast<const float4*>(&xs[rr][k4 * 4]);
            aq[rr] += x.x*wqv.x + x.y*wqv.y + x.z*wqv.z + x.w*wqv.w;
            ak[rr] += x.x*wkv.x + x.y*wkv.y + x.z*wkv.z + x.w*wkv.w;
            av[rr] += x.x*wvv.x + x.y*wvv.y + x.z*wvv.z + x.w*wvv.w;
        }
    }
    const float bqv = bq[c] + beq[c];
    const float bkv = bk[c] + bek[c];
    const float bvv = bv[c] + bev[c];
    const int h = c >> 5, d = c & 31;
    #pragma unroll
    for (int rr = 0; rr < 4; rr++) {
        const int g  = g0 + rr;
        const int bb = g >> 9, ii = g & (N_ - 1);
        size_t o = ((size_t)(bb * NH_ + h) * N_ + ii) * DH_ + d;
        Qh[o] = aq[rr] + bqv;
        Kh[o] = ak[rr] + bkv;
        Vh[o] = av[rr] + bvv;
    }
}

// ---------------- main fused kernel: 2 blocks per (b,i), 4 heads each -----
// 256 threads = 4 waves, wave w = head hh*4+w. e staged per 64-j chunk into
// double-buffered LDS (bf16, 72-short row stride). Q/K/V folded into MFMA
// C-operand. One barrier per 64 j.
__global__ __launch_bounds__(256, 4) void attn_kernel(
    const float* __restrict__ edge,
    const float* __restrict__ Qh, const float* __restrict__ Kh,
    const float* __restrict__ Vh, const unsigned short* __restrict__ W16,
    float* __restrict__ out)
{
    __shared__ unsigned short lds_[2][64 * 72];

    const int tid  = threadIdx.x;
    const int lane = tid & 63;
    const int w    = tid >> 6;       // 0..3
    const int q4   = lane >> 4;
    const int l15  = lane & 15;
    const int blk  = blockIdx.x;
    const int hh   = blk & 1;
    const int i    = (blk >> 1) & (N_ - 1);
    const int b    = blk >> 10;
    const int h    = hh * 4 + w;
    const int bh   = b * NH_ + h;

    // W A-operand frags: A[m=l15][k=q4*8+kk]; wf[m][half][ks]
    bf16x8 wf[3][2][2];
    #pragma unroll
    for (int m = 0; m < 3; m++)
        #pragma unroll
        for (int hf = 0; hf < 2; hf++)
            #pragma unroll
            for (int ks = 0; ks < 2; ks++) {
                const u32x4* p = reinterpret_cast<const u32x4*>(
                    W16 + m * (ND_ * ED_) + (h * DH_ + hf * 16 + l15) * ED_ + ks * 32 + q4 * 8);
                wf[m][hf][ks] = __builtin_bit_cast(bf16x8, *p);
            }

    // Q C-init (row d = q4*4+r, replicated over j=l15 — correct broadcast)
    const float* Qrow = Qh + ((size_t)bh * N_ + i) * DH_;
    const f32x4 Cq0 = *reinterpret_cast<const f32x4*>(Qrow + q4 * 4);
    const f32x4 Cq1 = *reinterpret_cast<const f32x4*>(Qrow + 16 + q4 * 4);

    const float* Kbase = Kh + (size_t)bh * N_ * DH_;
    const float* Vbase = Vh + (size_t)bh * N_ * DH_;
    const float* ebase = edge + (size_t)(b * N_ + i) * N_ * ED_;

    float m_run = -INFINITY, l_run = 0.f;
    f32x4 o0 = {0.f, 0.f, 0.f, 0.f}, o1 = {0.f, 0.f, 0.f, 0.f};
    const float scale = 0.17677669529663687f;   // 1/sqrt(32)

    // stage chunk 0 (64 j-rows = 4096 floats = 1024 float4; 4 per thread)
    const float4* ep = reinterpret_cast<const float4*>(ebase);
    float4 g0 = ep[tid], g1 = ep[tid + 256], g2 = ep[tid + 512], g3 = ep[tid + 768];
    {
        unsigned short* buf = lds_[0];
        const float4 gg[4] = {g0, g1, g2, g3};
        #pragma unroll
        for (int pt = 0; pt < 4; pt++) {
            const int f = tid + pt * 256;
            const int row = f >> 4, c4 = f & 15;
            uint2 v = {pack_bf16(gg[pt].x, gg[pt].y), pack_bf16(gg[pt].z, gg[pt].w)};
            *reinterpret_cast<uint2*>(buf + row * 72 + c4 * 4) = v;
        }
    }
    __syncthreads();

    #pragma unroll 1
    for (int ch = 0; ch < 8; ch++) {
        if (ch < 7) {   // issue next chunk's global loads early
            const float4* np = reinterpret_cast<const float4*>(ebase + (ch + 1) * 4096);
            g0 = np[tid]; g1 = np[tid + 256]; g2 = np[tid + 512]; g3 = np[tid + 768];
        }
        const unsigned short* buf = lds_[ch & 1];

        #pragma unroll 2
        for (int sub = 0; sub < 4; sub++) {
            const int j = ch * 64 + sub * 16 + l15;

            // e B-frags from LDS: B[k=q4*8+kk][n=j=l15]
            const unsigned short* arow = buf + (sub * 16 + l15) * 72 + q4 * 8;
            const bf16x8 a0 = __builtin_bit_cast(bf16x8, *reinterpret_cast<const u32x4*>(arow));
            const bf16x8 a1 = __builtin_bit_cast(bf16x8, *reinterpret_cast<const u32x4*>(arow + 32));

            // K/V C-init: element (reg r, lane) = K[j=l15][d=(hf*16)+q4*4+r]
            const float* Krow = Kbase + (size_t)j * DH_;
            const float* Vrow = Vbase + (size_t)j * DH_;
            const f32x4 Ck0 = *reinterpret_cast<const f32x4*>(Krow + q4 * 4);
            const f32x4 Ck1 = *reinterpret_cast<const f32x4*>(Krow + 16 + q4 * 4);
            const f32x4 Cv0 = *reinterpret_cast<const f32x4*>(Vrow + q4 * 4);
            const f32x4 Cv1 = *reinterpret_cast<const f32x4*>(Vrow + 16 + q4 * 4);

            f32x4 eq0 = __builtin_amdgcn_mfma_f32_16x16x32_bf16(wf[0][0][0], a0, Cq0, 0, 0, 0);
            f32x4 eq1 = __builtin_amdgcn_mfma_f32_16x16x32_bf16(wf[0][1][0], a0, Cq1, 0, 0, 0);
            f32x4 ek0 = __builtin_amdgcn_mfma_f32_16x16x32_bf16(wf[1][0][0], a0, Ck0, 0, 0, 0);
            f32x4 ek1 = __builtin_amdgcn_mfma_f32_16x16x32_bf16(wf[1][1][0], a0, Ck1, 0, 0, 0);
            f32x4 ev0 = __builtin_amdgcn_mfma_f32_16x16x32_bf16(wf[2][0][0], a0, Cv0, 0, 0, 0);
            f32x4 ev1 = __builtin_amdgcn_mfma_f32_16x16x32_bf16(wf[2][1][0], a0, Cv1, 0, 0, 0);
            eq0 = __builtin_amdgcn_mfma_f32_16x16x32_bf16(wf[0][0][1], a1, eq0, 0, 0, 0);
            eq1 = __builtin_amdgcn_mfma_f32_16x16x32_bf16(wf[0][1][1], a1, eq1, 0, 0, 0);
            ek0 = __builtin_amdgcn_mfma_f32_16x16x32_bf16(wf[1][0][1], a1, ek0, 0, 0, 0);
            ek1 = __builtin_amdgcn_mfma_f32_16x16x32_bf16(wf[1][1][1], a1, ek1, 0, 0, 0);
            ev0 = __builtin_amdgcn_mfma_f32_16x16x32_bf16(wf[2][0][1], a1, ev0, 0, 0, 0);
            ev1 = __builtin_amdgcn_mfma_f32_16x16x32_bf16(wf[2][1][1], a1, ev1, 0, 0, 0);

            // score for lane's j: full 32-d dot via in-lane 8 + quad reduce
            float t = eq0[0]*ek0[0] + eq0[1]*ek0[1] + eq0[2]*ek0[2] + eq0[3]*ek0[3]
                    + eq1[0]*ek1[0] + eq1[1]*ek1[1] + eq1[2]*ek1[2] + eq1[3]*ek1[3];
            t += __shfl_xor(t, 16, 64);
            t += __shfl_xor(t, 32, 64);
            const float s = t * scale;

            float tmax = s;
            tmax = fmaxf(tmax, __shfl_xor(tmax, 1, 64));
            tmax = fmaxf(tmax, __shfl_xor(tmax, 2, 64));
            tmax = fmaxf(tmax, __shfl_xor(tmax, 4, 64));
            tmax = fmaxf(tmax, __shfl_xor(tmax, 8, 64));
            const float m_new = fmaxf(m_run, tmax);
            const float alpha = __expf(m_run - m_new);
            const float p = __expf(s - m_new);
            float psum = p;
            psum += __shfl_xor(psum, 1, 64);
            psum += __shfl_xor(psum, 2, 64);
            psum += __shfl_xor(psum, 4, 64);
            psum += __shfl_xor(psum, 8, 64);
            l_run = l_run * alpha + psum;
            m_run = m_new;

            o0 = o0 * alpha + ev0 * p;
            o1 = o1 * alpha + ev1 * p;
        }

        if (ch < 7) {   // pack+store next chunk into the other buffer
            unsigned short* nbuf = lds_[(ch + 1) & 1];
            const float4 gg[4] = {g0, g1, g2, g3};
            #pragma unroll
            for (int pt = 0; pt < 4; pt++) {
                const int f = tid + pt * 256;
                const int row = f >> 4, c4 = f & 15;
                uint2 v = {pack_bf16(gg[pt].x, gg[pt].y), pack_bf16(gg[pt].z, gg[pt].w)};
                *reinterpret_cast<uint2*>(nbuf + row * 72 + c4 * 4) = v;
            }
        }
        __syncthreads();
    }

    // reduce PV partials over j-classes (l15 lanes); masks 1..8 stay in-quad
    #pragma unroll
    for (int mask = 1; mask <= 8; mask <<= 1) {
        #pragma unroll
        for (int r = 0; r < 4; r++) {
            o0[r] += __shfl_xor(o0[r], mask, 64);
            o1[r] += __shfl_xor(o1[r], mask, 64);
        }
    }
    const float inv = 1.f / l_run;
    if (l15 == 0) {
        float* orow = out + (size_t)(b * N_ + i) * ND_ + h * DH_ + q4 * 4;
        float4 va = {o0[0] * inv, o0[1] * inv, o0[2] * inv, o0[3] * inv};
        float4 vb = {o1[0] * inv, o1[1] * inv, o1[2] * inv, o1[3] * inv};
        *reinterpret_cast<float4*>(orow)      = va;
        *reinterpret_cast<float4*>(orow + 16) = vb;
    }
}

extern "C" void kernel_launch(void* const* d_in, const int* in_sizes, int n_in,
                              void* d_out, int out_size, void* d_ws, size_t ws_size,
                              hipStream_t stream) {
    const float* node = (const float*)d_in[0];
    const float* edge = (const float*)d_in[1];
    const float* Wnq  = (const float*)d_in[2];
    const float* bnq  = (const float*)d_in[3];
    const float* Wnk  = (const float*)d_in[4];
    const float* bnk  = (const float*)d_in[5];
    const float* Wnv  = (const float*)d_in[6];
    const float* bnv  = (const float*)d_in[7];
    const float* Weq  = (const float*)d_in[8];
    const float* beq  = (const float*)d_in[9];
    const float* Wek  = (const float*)d_in[10];
    const float* bek  = (const float*)d_in[11];
    const float* Wev  = (const float*)d_in[12];
    const float* bev  = (const float*)d_in[13];

    char* ws = (char*)d_ws;
    unsigned short* W16 = (unsigned short*)ws;              // 96 KB
    float* Qh = (float*)(ws + 131072);                      // 2 MB each
    float* Kh = Qh + (size_t)B_ * N_ * ND_;
    float* Vh = Kh + (size_t)B_ * N_ * ND_;
    float* out = (float*)d_out;

    cvt_w_kernel<<<192, 256, 0, stream>>>(Weq, Wek, Wev, W16);
    qkv_kernel<<<(B_ * N_) / 4, 256, 0, stream>>>(node, Wnq, bnq, Wnk, bnk, Wnv, bnv,
                                                  beq, bek, bev, Qh, Kh, Vh);
    attn_kernel<<<B_ * N_ * 2, 256, 0, stream>>>(edge, Qh, Kh, Vh, W16, out);
}

// Round 4
// 353.494 us; speedup vs baseline: 1.2675x; 1.1586x over previous
//
#include <hip/hip_runtime.h>

typedef __bf16 bf16x8 __attribute__((ext_vector_type(8)));
typedef float  f32x4  __attribute__((ext_vector_type(4)));
typedef unsigned int u32x4 __attribute__((ext_vector_type(4)));

#define B_   2
#define N_   512
#define ND_  256
#define ED_  64
#define NH_  8
#define DH_  32

static __device__ __forceinline__ unsigned pack_bf16(float a, float b) {
    unsigned short ua = __builtin_bit_cast(unsigned short, (__bf16)a);
    unsigned short ub = __builtin_bit_cast(unsigned short, (__bf16)b);
    return (unsigned)ua | ((unsigned)ub << 16);
}

// ---------------- prep kernel 1: edge-weight fp32 -> bf16 ----------------
__global__ __launch_bounds__(256) void cvt_w_kernel(
    const float* __restrict__ wq, const float* __restrict__ wk,
    const float* __restrict__ wv, unsigned short* __restrict__ w16)
{
    int id = blockIdx.x * 256 + threadIdx.x;          // 0..49151
    const float* src = (id < 16384) ? wq : (id < 32768 ? wk : wv);
    int idx = id & 16383;
    w16[id] = __builtin_bit_cast(unsigned short, (__bf16)src[idx]);
}

// ------- prep kernel 2: node projections, folded biases, HEAD-SPLIT ------
// Qh/Kh/Vh layout: [b*NH+h][N][DH] fp32 (matches MFMA C-operand load shape)
__global__ __launch_bounds__(256) void qkv_kernel(
    const float* __restrict__ node,
    const float* __restrict__ Wq, const float* __restrict__ bq,
    const float* __restrict__ Wk, const float* __restrict__ bk,
    const float* __restrict__ Wv, const float* __restrict__ bv,
    const float* __restrict__ beq, const float* __restrict__ bek,
    const float* __restrict__ bev,
    float* __restrict__ Qh, float* __restrict__ Kh, float* __restrict__ Vh)
{
    __shared__ float xs[4][ND_];
    const int c  = threadIdx.x;
    const int g0 = blockIdx.x * 4;
    #pragma unroll
    for (int rr = 0; rr < 4; rr++) xs[rr][c] = node[(size_t)(g0 + rr) * ND_ + c];
    __syncthreads();

    float aq[4] = {}, ak[4] = {}, av[4] = {};
    const float4* wqr = reinterpret_cast<const float4*>(Wq + (size_t)c * ND_);
    const float4* wkr = reinterpret_cast<const float4*>(Wk + (size_t)c * ND_);
    const float4* wvr = reinterpret_cast<const float4*>(Wv + (size_t)c * ND_);
    for (int k4 = 0; k4 < ND_ / 4; k4++) {
        float4 wqv = wqr[k4], wkv = wkr[k4], wvv = wvr[k4];
        #pragma unroll
        for (int rr = 0; rr < 4; rr++) {
            const float4 x = *reinterpret_cast<const float4*>(&xs[rr][k4 * 4]);
            aq[rr] += x.x*wqv.x + x.y*wqv.y + x.z*wqv.z + x.w*wqv.w;
            ak[rr] += x.x*wkv.x + x.y*wkv.y + x.z*wkv.z + x.w*wkv.w;
            av[rr] += x.x*wvv.x + x.y*wvv.y + x.z*wvv.z + x.w*wvv.w;
        }
    }
    const float bqv = bq[c] + beq[c];
    const float bkv = bk[c] + bek[c];
    const float bvv = bv[c] + bev[c];
    const int h = c >> 5, d = c & 31;
    #pragma unroll
    for (int rr = 0; rr < 4; rr++) {
        const int g  = g0 + rr;
        const int bb = g >> 9, ii = g & (N_ - 1);
        size_t o = ((size_t)(bb * NH_ + h) * N_ + ii) * DH_ + d;
        Qh[o] = aq[rr] + bqv;
        Kh[o] = ak[rr] + bkv;
        Vh[o] = av[rr] + bvv;
    }
}

// ---------------- main fused kernel: one block per (b,i), 8 waves = 8 heads
// e staged per 64-j chunk, double-buffered LDS. Q/K/V folded into MFMA C.
// NO online softmax: p = exp(s - 4) (shift cancels in normalization); l and
// o accumulate per-lane with no in-loop cross-lane except the 2-shfl score
// reduce. One barrier per 64 j.
__global__ __launch_bounds__(512, 4) void attn_kernel(
    const float* __restrict__ edge,
    const float* __restrict__ Qh, const float* __restrict__ Kh,
    const float* __restrict__ Vh, const unsigned short* __restrict__ W16,
    float* __restrict__ out)
{
    __shared__ unsigned short lds_[2][64 * 72];

    const int tid  = threadIdx.x;
    const int lane = tid & 63;
    const int h    = tid >> 6;       // wave id == head
    const int q4   = lane >> 4;
    const int l15  = lane & 15;
    const int blk  = blockIdx.x;
    const int b    = blk >> 9;
    const int i    = blk & (N_ - 1);
    const int bh   = b * NH_ + h;

    // W A-operand frags: A[m=l15][k=q4*8+kk]; wf[m][half][ks]
    bf16x8 wf[3][2][2];
    #pragma unroll
    for (int m = 0; m < 3; m++)
        #pragma unroll
        for (int hf = 0; hf < 2; hf++)
            #pragma unroll
            for (int ks = 0; ks < 2; ks++) {
                const u32x4* p = reinterpret_cast<const u32x4*>(
                    W16 + m * (ND_ * ED_) + (h * DH_ + hf * 16 + l15) * ED_ + ks * 32 + q4 * 8);
                wf[m][hf][ks] = __builtin_bit_cast(bf16x8, *p);
            }

    // Q C-init (row d = q4*4+r, broadcast over j=l15)
    const float* Qrow = Qh + ((size_t)bh * N_ + i) * DH_;
    const f32x4 Cq0 = *reinterpret_cast<const f32x4*>(Qrow + q4 * 4);
    const f32x4 Cq1 = *reinterpret_cast<const f32x4*>(Qrow + 16 + q4 * 4);

    const float* Kbase = Kh + (size_t)bh * N_ * DH_;
    const float* Vbase = Vh + (size_t)bh * N_ * DH_;
    const float* ebase = edge + (size_t)blk * N_ * ED_;

    float l_acc = 0.f;
    f32x4 o0 = {0.f, 0.f, 0.f, 0.f}, o1 = {0.f, 0.f, 0.f, 0.f};
    const float scale = 0.17677669529663687f;   // 1/sqrt(32)

    // stage chunk 0 (64 j-rows = 4096 floats = 1024 float4; 2 per thread)
    const float4* ep = reinterpret_cast<const float4*>(ebase);
    float4 g0 = ep[tid], g1 = ep[tid + 512];
    {
        unsigned short* buf = lds_[0];
        #pragma unroll
        for (int pt = 0; pt < 2; pt++) {
            const float4 g = pt ? g1 : g0;
            const int f = tid + pt * 512;
            const int row = f >> 4, c4 = f & 15;
            uint2 v = {pack_bf16(g.x, g.y), pack_bf16(g.z, g.w)};
            *reinterpret_cast<uint2*>(buf + row * 72 + c4 * 4) = v;
        }
    }
    __syncthreads();

    #pragma unroll 1
    for (int ch = 0; ch < 8; ch++) {
        if (ch < 7) {   // issue next chunk's global loads early
            const float4* np = reinterpret_cast<const float4*>(ebase + (ch + 1) * 4096);
            g0 = np[tid]; g1 = np[tid + 512];
        }
        const unsigned short* buf = lds_[ch & 1];

        #pragma unroll 2
        for (int sub = 0; sub < 4; sub++) {
            const int j = ch * 64 + sub * 16 + l15;

            // e B-frags from LDS: B[k=q4*8+kk][n=j=l15]
            const unsigned short* arow = buf + (sub * 16 + l15) * 72 + q4 * 8;
            const bf16x8 a0 = __builtin_bit_cast(bf16x8, *reinterpret_cast<const u32x4*>(arow));
            const bf16x8 a1 = __builtin_bit_cast(bf16x8, *reinterpret_cast<const u32x4*>(arow + 32));

            // K/V C-init: element (reg r, lane) = K[j=l15][(hf*16)+q4*4+r]
            const float* Krow = Kbase + (size_t)j * DH_;
            const float* Vrow = Vbase + (size_t)j * DH_;
            const f32x4 Ck0 = *reinterpret_cast<const f32x4*>(Krow + q4 * 4);
            const f32x4 Ck1 = *reinterpret_cast<const f32x4*>(Krow + 16 + q4 * 4);
            const f32x4 Cv0 = *reinterpret_cast<const f32x4*>(Vrow + q4 * 4);
            const f32x4 Cv1 = *reinterpret_cast<const f32x4*>(Vrow + 16 + q4 * 4);

            f32x4 eq0 = __builtin_amdgcn_mfma_f32_16x16x32_bf16(wf[0][0][0], a0, Cq0, 0, 0, 0);
            f32x4 eq1 = __builtin_amdgcn_mfma_f32_16x16x32_bf16(wf[0][1][0], a0, Cq1, 0, 0, 0);
            f32x4 ek0 = __builtin_amdgcn_mfma_f32_16x16x32_bf16(wf[1][0][0], a0, Ck0, 0, 0, 0);
            f32x4 ek1 = __builtin_amdgcn_mfma_f32_16x16x32_bf16(wf[1][1][0], a0, Ck1, 0, 0, 0);
            f32x4 ev0 = __builtin_amdgcn_mfma_f32_16x16x32_bf16(wf[2][0][0], a0, Cv0, 0, 0, 0);
            f32x4 ev1 = __builtin_amdgcn_mfma_f32_16x16x32_bf16(wf[2][1][0], a0, Cv1, 0, 0, 0);
            eq0 = __builtin_amdgcn_mfma_f32_16x16x32_bf16(wf[0][0][1], a1, eq0, 0, 0, 0);
            eq1 = __builtin_amdgcn_mfma_f32_16x16x32_bf16(wf[0][1][1], a1, eq1, 0, 0, 0);
            ek0 = __builtin_amdgcn_mfma_f32_16x16x32_bf16(wf[1][0][1], a1, ek0, 0, 0, 0);
            ek1 = __builtin_amdgcn_mfma_f32_16x16x32_bf16(wf[1][1][1], a1, ek1, 0, 0, 0);
            ev0 = __builtin_amdgcn_mfma_f32_16x16x32_bf16(wf[2][0][1], a1, ev0, 0, 0, 0);
            ev1 = __builtin_amdgcn_mfma_f32_16x16x32_bf16(wf[2][1][1], a1, ev1, 0, 0, 0);

            // score for lane's j (quad-reduce over d), then unnormalized exp
            float t = eq0[0]*ek0[0] + eq0[1]*ek0[1] + eq0[2]*ek0[2] + eq0[3]*ek0[3]
                    + eq1[0]*ek1[0] + eq1[1]*ek1[1] + eq1[2]*ek1[2] + eq1[3]*ek1[3];
            t += __shfl_xor(t, 16, 64);
            t += __shfl_xor(t, 32, 64);
            const float p = __expf(fmaf(t, scale, -4.f));   // shift cancels in norm

            l_acc += p;
            o0 += ev0 * p;
            o1 += ev1 * p;
        }

        if (ch < 7) {   // pack+store next chunk into the other buffer
            unsigned short* nbuf = lds_[(ch + 1) & 1];
            #pragma unroll
            for (int pt = 0; pt < 2; pt++) {
                const float4 g = pt ? g1 : g0;
                const int f = tid + pt * 512;
                const int row = f >> 4, c4 = f & 15;
                uint2 v = {pack_bf16(g.x, g.y), pack_bf16(g.z, g.w)};
                *reinterpret_cast<uint2*>(nbuf + row * 72 + c4 * 4) = v;
            }
        }
        __syncthreads();
    }

    // final reductions over the 16 j-classes (l15); masks 1..8 stay in-quad
    #pragma unroll
    for (int mask = 1; mask <= 8; mask <<= 1) {
        l_acc += __shfl_xor(l_acc, mask, 64);
        #pragma unroll
        for (int r = 0; r < 4; r++) {
            o0[r] += __shfl_xor(o0[r], mask, 64);
            o1[r] += __shfl_xor(o1[r], mask, 64);
        }
    }
    const float inv = 1.f / l_acc;
    if (l15 == 0) {
        float* orow = out + (size_t)(b * N_ + i) * ND_ + h * DH_ + q4 * 4;
        float4 va = {o0[0] * inv, o0[1] * inv, o0[2] * inv, o0[3] * inv};
        float4 vb = {o1[0] * inv, o1[1] * inv, o1[2] * inv, o1[3] * inv};
        *reinterpret_cast<float4*>(orow)      = va;
        *reinterpret_cast<float4*>(orow + 16) = vb;
    }
}

extern "C" void kernel_launch(void* const* d_in, const int* in_sizes, int n_in,
                              void* d_out, int out_size, void* d_ws, size_t ws_size,
                              hipStream_t stream) {
    const float* node = (const float*)d_in[0];
    const float* edge = (const float*)d_in[1];
    const float* Wnq  = (const float*)d_in[2];
    const float* bnq  = (const float*)d_in[3];
    const float* Wnk  = (const float*)d_in[4];
    const float* bnk  = (const float*)d_in[5];
    const float* Wnv  = (const float*)d_in[6];
    const float* bnv  = (const float*)d_in[7];
    const float* Weq  = (const float*)d_in[8];
    const float* beq  = (const float*)d_in[9];
    const float* Wek  = (const float*)d_in[10];
    const float* bek  = (const float*)d_in[11];
    const float* Wev  = (const float*)d_in[12];
    const float* bev  = (const float*)d_in[13];

    char* ws = (char*)d_ws;
    unsigned short* W16 = (unsigned short*)ws;              // 96 KB
    float* Qh = (float*)(ws + 131072);
    float* Kh = Qh + (size_t)B_ * N_ * ND_;
    float* Vh = Kh + (size_t)B_ * N_ * ND_;
    float* out = (float*)d_out;

    cvt_w_kernel<<<192, 256, 0, stream>>>(Weq, Wek, Wev, W16);
    qkv_kernel<<<(B_ * N_) / 4, 256, 0, stream>>>(node, Wnq, bnq, Wnk, bnk, Wnv, bnv,
                                                  beq, bek, bev, Qh, Kh, Vh);
    attn_kernel<<<B_ * N_, 512, 0, stream>>>(edge, Qh, Kh, Vh, W16, out);
}